// Round 9
// baseline (335.898 us; speedup 1.0000x reference)
//
#include <hip/hip_runtime.h>

#define DIM 128
#define BN_EPS 1e-5f

typedef float f32x4 __attribute__((ext_vector_type(4)));
typedef short s16x8 __attribute__((ext_vector_type(8)));

// ---- bf16 helpers ----
__device__ __forceinline__ float bflo(unsigned int h) {
    return __uint_as_float(h << 16);
}
__device__ __forceinline__ float bfhi(unsigned int h) {
    return __uint_as_float(h & 0xffff0000u);
}
__device__ __forceinline__ unsigned int f2bf(float f) {
    unsigned int u = __float_as_uint(f);
    return (u + 0x7fffu + ((u >> 16) & 1u)) >> 16;   // round-to-nearest-even
}
__device__ __forceinline__ unsigned int pack2(float a, float b) {
    return f2bf(a) | (f2bf(b) << 16);
}

// ---------------------------------------------------------------------------
// init: zero degree counters and BN stats accumulators (2 x [sum128|sumsq128])
__global__ __launch_bounds__(256) void k_init(int* __restrict__ deg_cnt,
                                              float* __restrict__ stats, int n) {
    int i = blockIdx.x * 256 + threadIdx.x;
    if (i < n) deg_cnt[i] = 0;
    if (i < 512) stats[i] = 0.0f;
}

// one-time: split W1,W2 (128x128 fp32) into bf16 hi/lo planes in MFMA
// B-fragment order: Wp[((k>>5)*4 + ((k>>3)&3))*128 + col][k&7].
__global__ __launch_bounds__(256) void k_wprep(const float* __restrict__ W1,
                                               unsigned short* __restrict__ W1h,
                                               unsigned short* __restrict__ W1l,
                                               const float* __restrict__ W2,
                                               unsigned short* __restrict__ W2h,
                                               unsigned short* __restrict__ W2l) {
    int idx = blockIdx.x * 256 + threadIdx.x;   // 16384
    int k = idx >> 7;
    int col = idx & 127;
    int dst = ((((k >> 5) * 4 + ((k >> 3) & 3)) * 128) + col) * 8 + (k & 7);
    {
        float v = W1[idx];
        unsigned int hi = f2bf(v);
        unsigned int lo = f2bf(v - __uint_as_float(hi << 16));
        W1h[dst] = (unsigned short)hi;
        W1l[dst] = (unsigned short)lo;
    }
    {
        float v = W2[idx];
        unsigned int hi = f2bf(v);
        unsigned int lo = f2bf(v - __uint_as_float(hi << 16));
        W2h[dst] = (unsigned short)hi;
        W2l[dst] = (unsigned short)lo;
    }
}

// in-degree histogram over dst; 4 edges/thread (round-0 measured config)
__global__ __launch_bounds__(256) void k_deg(const int* __restrict__ dst,
                                             int* __restrict__ deg_cnt, int e) {
    int base = blockIdx.x * 1024 + threadIdx.x;
    int i0 = base, i1 = base + 256, i2 = base + 512, i3 = base + 768;
    int d0 = (i0 < e) ? dst[i0] : -1;
    int d1 = (i1 < e) ? dst[i1] : -1;
    int d2 = (i2 < e) ? dst[i2] : -1;
    int d3 = (i3 < e) ? dst[i3] : -1;
    if (d0 >= 0) atomicAdd(&deg_cnt[d0], 1);
    if (d1 >= 0) atomicAdd(&deg_cnt[d1], 1);
    if (d2 >= 0) atomicAdd(&deg_cnt[d2], 1);
    if (d3 >= 0) atomicAdd(&deg_cnt[d3], 1);
}

// ---------------------------------------------------------------------------
__device__ __forceinline__ int wave_scan_incl(int v) {
    int lane = threadIdx.x & 63;
#pragma unroll
    for (int off = 1; off < 64; off <<= 1) {
        int t = __shfl_up(v, off, 64);
        if (lane >= off) v += t;
    }
    return v;
}

// stage 1: local exclusive scan -> row_start; block totals; also dinv
__global__ __launch_bounds__(256) void k_scan1(const int* __restrict__ deg_cnt,
                                               int* __restrict__ row_start,
                                               int* __restrict__ blk_sum,
                                               float* __restrict__ dinv, int n) {
    int tid = threadIdx.x;
    int i = blockIdx.x * 256 + tid;
    int v = (i < n) ? deg_cnt[i] : 0;
    if (i < n) dinv[i] = rsqrtf((float)v + 1.0f);   // fused: self-loop adds 1
    int inc = wave_scan_incl(v);
    __shared__ int wtot[4];
    int wave = tid >> 6, lane = tid & 63;
    if (lane == 63) wtot[wave] = inc;
    __syncthreads();
    int woff = 0;
    for (int w = 0; w < wave; ++w) woff += wtot[w];
    int excl = woff + inc - v;
    if (i < n) row_start[i] = excl;
    if (tid == 255) blk_sum[blockIdx.x] = woff + inc;
}

// stage 2+3 fused: each block redundantly reduces its exclusive block-prefix
// from blk_sum (nblk <= 256), applies it, block 0 writes the grand total.
__global__ __launch_bounds__(256) void k_scan3(int* __restrict__ row_start,
                                               const int* __restrict__ blk_sum,
                                               int* __restrict__ cursor,
                                               int n, int nblk) {
    __shared__ int wp[4], wv[4];
    __shared__ int s_off, s_tot;
    int tid = threadIdx.x;
    int v   = (tid < nblk) ? blk_sum[tid] : 0;
    int pre = (tid < (int)blockIdx.x) ? v : 0;
    int lane = tid & 63, wave = tid >> 6;
#pragma unroll
    for (int off = 32; off > 0; off >>= 1) {
        pre += __shfl_down(pre, off, 64);
        v   += __shfl_down(v,   off, 64);
    }
    if (lane == 0) { wp[wave] = pre; wv[wave] = v; }
    __syncthreads();
    if (tid == 0) {
        s_off = wp[0] + wp[1] + wp[2] + wp[3];
        s_tot = wv[0] + wv[1] + wv[2] + wv[3];
    }
    __syncthreads();
    int i = blockIdx.x * 256 + tid;
    if (i < n) {
        int rs = row_start[i] + s_off;
        row_start[i] = rs;
        cursor[i] = rs;
    }
    if (blockIdx.x == 0 && tid == 0) row_start[n] = s_tot;   // grand total
}

// ---------------------------------------------------------------------------
// MFMA GEMM tile (validated r8): H[r0b..r0b+63, :] = bf16( BNReLU?(X) @ W ).
// 3-MFMA hi/lo split for ~fp32 numerics. 4 waves of 32x64 each.
// A staged in LDS as bf16 hi/lo in frag layout [kg][row][kj];
// B read from pre-permuted global planes (64 KB, L2-resident).
__device__ __forceinline__ void gemm_tile_mfma(
        const float* __restrict__ X,
        const unsigned short* __restrict__ Wh,
        const unsigned short* __restrict__ Wl,
        unsigned short* __restrict__ H,
        int n, int r0b,
        const float* __restrict__ bnsc,   // null -> raw X
        const float* __restrict__ bnsh,
        unsigned short (*xsh)[64][8],     // [4][64][8] 4 KB
        unsigned short (*xsl)[64][8]) {   // [4][64][8] 4 KB
    int t = threadIdx.x;
    int wid  = t >> 6;
    int lane = t & 63;
    int wrow = (wid & 1) * 32;
    int wcol = (wid >> 1) * 64;
    int lr = lane & 15;
    int kg = lane >> 4;
    bool bn = (bnsc != nullptr);

    const float4* X4 = (const float4*)X;
    f32x4 acc[2][4];
#pragma unroll
    for (int h = 0; h < 2; ++h)
#pragma unroll
        for (int c = 0; c < 4; ++c) acc[h][c] = (f32x4)0.f;

    for (int ks = 0; ks < 4; ++ks) {     // K-steps of 32
        if (ks) __syncthreads();
#pragma unroll
        for (int i = 0; i < 2; ++i) {
            int idx = t * 2 + i;         // 0..511
            int row = idx >> 3;          // 0..63
            int kq  = idx & 7;           // float4 within 32 k
            float4 v = make_float4(0.f, 0.f, 0.f, 0.f);
            if (r0b + row < n)
                v = X4[(size_t)(r0b + row) * 32 + ks * 8 + kq];
            if (bn) {
                int ch = ks * 32 + kq * 4;
                v.x = fmaxf(v.x * bnsc[ch + 0] + bnsh[ch + 0], 0.f);
                v.y = fmaxf(v.y * bnsc[ch + 1] + bnsh[ch + 1], 0.f);
                v.z = fmaxf(v.z * bnsc[ch + 2] + bnsh[ch + 2], 0.f);
                v.w = fmaxf(v.w * bnsc[ch + 3] + bnsh[ch + 3], 0.f);
            }
            unsigned int hx = f2bf(v.x), hy = f2bf(v.y), hz = f2bf(v.z), hw = f2bf(v.w);
            float rx = v.x - bflo(hx), ry = v.y - bflo(hy);
            float rz = v.z - bflo(hz), rw = v.w - bflo(hw);
            uint2 hp = make_uint2(hx | (hy << 16), hz | (hw << 16));
            uint2 lp = make_uint2(f2bf(rx) | (f2bf(ry) << 16), f2bf(rz) | (f2bf(rw) << 16));
            *(uint2*)&xsh[kq >> 1][row][(kq & 1) * 4] = hp;
            *(uint2*)&xsl[kq >> 1][row][(kq & 1) * 4] = lp;
        }
        __syncthreads();

        s16x8 Ah[2], Al[2];
#pragma unroll
        for (int h = 0; h < 2; ++h) {
            int row = wrow + h * 16 + lr;
            Ah[h] = *(const s16x8*)&xsh[kg][row][0];
            Al[h] = *(const s16x8*)&xsl[kg][row][0];
        }
#pragma unroll
        for (int c = 0; c < 4; ++c) {
            int col = wcol + c * 16 + lr;
            size_t boff = ((size_t)((ks * 4 + kg) * 128 + col)) * 8;
            s16x8 Bh = *(const s16x8*)&Wh[boff];
            s16x8 Bl = *(const s16x8*)&Wl[boff];
#pragma unroll
            for (int h = 0; h < 2; ++h) {
                acc[h][c] = __builtin_amdgcn_mfma_f32_16x16x32_bf16(Ah[h], Bh, acc[h][c], 0, 0, 0);
                acc[h][c] = __builtin_amdgcn_mfma_f32_16x16x32_bf16(Al[h], Bh, acc[h][c], 0, 0, 0);
                acc[h][c] = __builtin_amdgcn_mfma_f32_16x16x32_bf16(Ah[h], Bl, acc[h][c], 0, 0, 0);
            }
        }
    }
    // C/D layout: col = lane&15, row = (lane>>4)*4 + r  [HW-verified]
#pragma unroll
    for (int h = 0; h < 2; ++h)
#pragma unroll
        for (int c = 0; c < 4; ++c)
#pragma unroll
            for (int r = 0; r < 4; ++r) {
                int row = r0b + wrow + h * 16 + kg * 4 + r;
                if (row < n)
                    H[(size_t)row * DIM + wcol + c * 16 + lr] =
                        (unsigned short)f2bf(acc[h][c][r]);
            }
}

// ---------------------------------------------------------------------------
// FUSED fill || MFMA GEMM1, 1:1 interleave while gemm blocks last (round-0
// mapping): even blocks gemm (782 of them, 64-row tiles), rest fill with
// 2 edges/thread. Early phase 1:1 mixed, tail pure fill.
__global__ __launch_bounds__(256) void k_fill_gemm(
        const int* __restrict__ src, const int* __restrict__ dst,
        const float* __restrict__ dinv, int* __restrict__ cursor,
        int2* __restrict__ edge, int e, int gemmBlocks,
        const float* __restrict__ X,
        const unsigned short* __restrict__ Wh,
        const unsigned short* __restrict__ Wl,
        unsigned short* __restrict__ H, int n) {
    __shared__ unsigned short xsh[4][64][8];   // 4 KB
    __shared__ unsigned short xsl[4][64][8];   // 4 KB

    int b = (int)blockIdx.x;
    bool isGemm = ((b & 1) == 0) && ((b >> 1) < gemmBlocks);
    if (!isGemm) {
        int nG = min(gemmBlocks, (b + 1) >> 1);   // gemm blocks before b
        int base = (b - nG) * 512 + threadIdx.x;
        int i0 = base, i1 = base + 256;
        bool v0 = i0 < e, v1 = i1 < e;
        int s0 = v0 ? src[i0] : 0, t0 = v0 ? dst[i0] : 0;
        int s1 = v1 ? src[i1] : 0, t1 = v1 ? dst[i1] : 0;
        float w0 = v0 ? dinv[s0] * dinv[t0] : 0.f;
        float w1 = v1 ? dinv[s1] * dinv[t1] : 0.f;
        if (v0) {
            int pos = atomicAdd(&cursor[t0], 1);
            edge[pos] = make_int2(s0, __float_as_int(w0));
        }
        if (v1) {
            int pos = atomicAdd(&cursor[t1], 1);
            edge[pos] = make_int2(s1, __float_as_int(w1));
        }
        return;
    }
    gemm_tile_mfma(X, Wh, Wl, H, n, (b >> 1) * 64, nullptr, nullptr, xsh, xsl);
}

// ---------------------------------------------------------------------------
// MFMA GEMM for conv2 (BN1+ReLU fused into staging) — validated r8.
__global__ __launch_bounds__(256) void k_gemm_mfma(
        const float* __restrict__ X,
        const unsigned short* __restrict__ Wh,
        const unsigned short* __restrict__ Wl,
        const float* __restrict__ stats,
        const float* __restrict__ gamma,
        const float* __restrict__ beta,
        unsigned short* __restrict__ H,
        int n, float invN) {
    __shared__ unsigned short xsh[4][64][8];   // 4 KB
    __shared__ unsigned short xsl[4][64][8];   // 4 KB
    __shared__ float bnsc[DIM], bnsh[DIM];
    int t = threadIdx.x;
    if (t < DIM) {
        float mu = stats[t] * invN;
        float var = stats[DIM + t] * invN - mu * mu;
        float inv = rsqrtf(var + BN_EPS);
        float sc = gamma[t] * inv;
        bnsc[t] = sc;
        bnsh[t] = beta[t] - mu * sc;
    }
    __syncthreads();
    gemm_tile_mfma(X, Wh, Wl, H, n, blockIdx.x * 64, bnsc, bnsh, xsh, xsl);
}

// ---------------------------------------------------------------------------
// out[i,:] = sum_{j in in-edges(i)} H[edge[j].x,:]*edge[j].w + H[i,:]*dinv[i]^2 + bias
// ONE WAVE per node; 16-edge main unroll + 4-step mid + scalar tail.
// (round-0 measured-best form; 4 alternatives all measured worse)
__global__ __launch_bounds__(256) void k_agg(const unsigned int* __restrict__ Hp,
                                             const float* __restrict__ bias,
                                             const float* __restrict__ dinv,
                                             const int* __restrict__ row_start,
                                             const int2* __restrict__ edge,
                                             float* __restrict__ out, int n, int e) {
    int node = blockIdx.x * 4 + (threadIdx.x >> 6);
    int lane = threadIdx.x & 63;
    if (node >= n) return;
    float di = dinv[node];
    float dsq = di * di;
    float b0 = bias[2 * lane];
    float b1 = bias[2 * lane + 1];
    unsigned int hs = Hp[(size_t)node * 64 + lane];
    float a0 = bflo(hs) * dsq + b0;
    float a1 = bfhi(hs) * dsq + b1;
    int jb = row_start[node], je = row_start[node + 1];
    jb = min(max(jb, 0), e);
    je = min(max(je, jb), e);
    int j = jb;
    for (; j + 16 <= je; j += 16) {
        int2 ed[16]; unsigned int h[16];
#pragma unroll
        for (int u = 0; u < 16; ++u) ed[u] = edge[j + u];
#pragma unroll
        for (int u = 0; u < 16; ++u) h[u] = Hp[(size_t)ed[u].x * 64 + lane];
#pragma unroll
        for (int u = 0; u < 16; ++u) {
            float w = __int_as_float(ed[u].y);
            a0 += bflo(h[u]) * w;
            a1 += bfhi(h[u]) * w;
        }
    }
    for (; j + 4 <= je; j += 4) {
        int2 ed[4]; unsigned int h[4];
#pragma unroll
        for (int u = 0; u < 4; ++u) ed[u] = edge[j + u];
#pragma unroll
        for (int u = 0; u < 4; ++u) h[u] = Hp[(size_t)ed[u].x * 64 + lane];
#pragma unroll
        for (int u = 0; u < 4; ++u) {
            float w = __int_as_float(ed[u].y);
            a0 += bflo(h[u]) * w;
            a1 += bfhi(h[u]) * w;
        }
    }
    for (; j < je; ++j) {
        int2 ed = edge[j];
        float w = __int_as_float(ed.y);
        unsigned int h = Hp[(size_t)ed.x * 64 + lane];
        a0 += bflo(h) * w;
        a1 += bfhi(h) * w;
    }
    out[(size_t)node * DIM + 2 * lane]     = a0;
    out[(size_t)node * DIM + 2 * lane + 1] = a1;
}

// ---------------------------------------------------------------------------
// column sums + sums of squares; 64 rows/block for latency hiding
__global__ __launch_bounds__(256) void k_stats(const float* __restrict__ V,
                                               float* __restrict__ sums, int n) {
    int d = threadIdx.x & 127;
    int half = threadIdx.x >> 7;
    int r0 = blockIdx.x * 64;
    int r1 = min(r0 + 64, n);
    float s = 0.f, q = 0.f;
    for (int r = r0 + half; r < r1; r += 2) {
        float v = V[(size_t)r * DIM + d];
        s += v; q += v * v;
    }
    __shared__ float ls[256], lq[256];
    ls[threadIdx.x] = s; lq[threadIdx.x] = q;
    __syncthreads();
    if (half == 0) {
        atomicAdd(&sums[d], s + ls[threadIdx.x + 128]);
        atomicAdd(&sums[128 + d], q + lq[threadIdx.x + 128]);
    }
}

// ---------------------------------------------------------------------------
// BN + residual + ReLU -> out (grid-stride float4; safe when V == out).
__global__ __launch_bounds__(256) void k_bn_res_relu(const float* __restrict__ V,
                                                     const float* __restrict__ X,
                                                     const float* __restrict__ stats,
                                                     const float* __restrict__ gamma,
                                                     const float* __restrict__ beta,
                                                     float* __restrict__ out,
                                                     int n, float invN) {
    __shared__ float bnsc[DIM], bnsh[DIM];
    int t = threadIdx.x;
    if (t < DIM) {
        float mu = stats[t] * invN;
        float var = stats[DIM + t] * invN - mu * mu;
        float inv = rsqrtf(var + BN_EPS);
        float sc = gamma[t] * inv;
        bnsc[t] = sc;
        bnsh[t] = beta[t] - mu * sc;
    }
    __syncthreads();
    int total4 = n * (DIM / 4);
    const float4* V4 = (const float4*)V;
    const float4* X4 = (const float4*)X;
    float4* O4 = (float4*)out;
    for (int i = blockIdx.x * 256 + t; i < total4; i += gridDim.x * 256) {
        int c = (i & 31) * 4;
        float4 v = V4[i];
        float4 x = X4[i];
        float4 o;
        o.x = fmaxf(v.x * bnsc[c + 0] + bnsh[c + 0] + x.x, 0.f);
        o.y = fmaxf(v.y * bnsc[c + 1] + bnsh[c + 1] + x.y, 0.f);
        o.z = fmaxf(v.z * bnsc[c + 2] + bnsh[c + 2] + x.z, 0.f);
        o.w = fmaxf(v.w * bnsc[c + 3] + bnsh[c + 3] + x.w, 0.f);
        O4[i] = o;
    }
}

// ---------------------------------------------------------------------------
extern "C" void kernel_launch(void* const* d_in, const int* in_sizes, int n_in,
                              void* d_out, int out_size, void* d_ws, size_t ws_size,
                              hipStream_t stream) {
    const float* x      = (const float*)d_in[0];
    const int*   ei     = (const int*)d_in[1];
    const float* W1     = (const float*)d_in[2];
    const float* b1     = (const float*)d_in[3];
    const float* gamma1 = (const float*)d_in[4];
    const float* beta1  = (const float*)d_in[5];
    const float* W2     = (const float*)d_in[6];
    const float* b2     = (const float*)d_in[7];
    const float* gamma2 = (const float*)d_in[8];
    const float* beta2  = (const float*)d_in[9];
    float* out = (float*)d_out;

    int n = in_sizes[0] / DIM;   // 50000
    int e = in_sizes[1] / 2;     // 800000
    const int* srcIdx = ei;
    const int* dstIdx = ei + e;

    int gN      = (n + 255) / 256;
    int gE4     = (e + 1023) / 1024;
    int gF2     = (e + 511) / 512;
    int gRows64 = (n + 63) / 64;
    int gNode   = (n + 3) / 4;
    int gS      = (n + 63) / 64;
    int gFin    = 1536;
    float invN = 1.0f / (float)n;

    char* ws = (char*)d_ws;
    size_t off = 0;
    auto alloc = [&](size_t bytes) -> void* {
        void* p = ws + off;
        off += (bytes + 255) & ~(size_t)255;
        return p;
    };
    int*   deg_cnt   = (int*)  alloc((size_t)n * 4);
    float* dinv      = (float*)alloc((size_t)n * 4);
    int*   row_start = (int*)  alloc((size_t)(n + 1) * 4);
    int*   cursor    = (int*)  alloc((size_t)n * 4);
    int*   blk_sum   = (int*)  alloc((size_t)gN * 4);
    int2*  edge      = (int2*) alloc((size_t)e * 8);
    unsigned short* Hb  = (unsigned short*)alloc((size_t)n * DIM * 2);
    unsigned short* W1h = (unsigned short*)alloc(16384 * 2);
    unsigned short* W1l = (unsigned short*)alloc(16384 * 2);
    unsigned short* W2h = (unsigned short*)alloc(16384 * 2);
    unsigned short* W2l = (unsigned short*)alloc(16384 * 2);
    float* stats     = (float*)alloc(512 * 4);
    float* stats1 = stats;
    float* stats2 = stats + 256;
    float* bufB = out;   // d_out doubles as fp32 N x D buffer

    if (off > ws_size || gN > 256) return;

    // graph preprocessing + one-time W1/W2 split/permute
    k_init<<<gN, 256, 0, stream>>>(deg_cnt, stats, n);
    k_wprep<<<64, 256, 0, stream>>>(W1, W1h, W1l, W2, W2h, W2l);
    k_deg<<<gE4, 256, 0, stream>>>(dstIdx, deg_cnt, e);
    k_scan1<<<gN, 256, 0, stream>>>(deg_cnt, row_start, blk_sum, dinv, n);
    k_scan3<<<gN, 256, 0, stream>>>(row_start, blk_sum, cursor, n, gN);

    // FUSED: CSR fill || MFMA GEMM1
    k_fill_gemm<<<gF2 + gRows64, 256, 0, stream>>>(
        srcIdx, dstIdx, dinv, cursor, edge, e, gRows64,
        x, W1h, W1l, Hb, n);

    // conv1 aggregation + stats
    k_agg<<<gNode, 256, 0, stream>>>((const unsigned int*)Hb, b1, dinv, row_start, edge, bufB, n, e);
    k_stats<<<gS, 256, 0, stream>>>(bufB, stats1, n);

    // conv2: MFMA GEMM (BN1+ReLU fused into staging)
    k_gemm_mfma<<<gRows64, 256, 0, stream>>>(bufB, W2h, W2l, stats1, gamma1, beta1, Hb, n, invN);
    k_agg<<<gNode, 256, 0, stream>>>((const unsigned int*)Hb, b2, dinv, row_start, edge, bufB, n, e);
    k_stats<<<gS, 256, 0, stream>>>(bufB, stats2, n);
    k_bn_res_relu<<<gFin, 256, 0, stream>>>(bufB, x, stats2, gamma2, beta2, out, n, invN);
}

// Round 10
// 316.727 us; speedup vs baseline: 1.0605x; 1.0605x over previous
//
#include <hip/hip_runtime.h>

#define DIM 128
#define BN_EPS 1e-5f

typedef float f32x4 __attribute__((ext_vector_type(4)));
typedef short s16x8 __attribute__((ext_vector_type(8)));

// ---- bf16 helpers ----
__device__ __forceinline__ float bflo(unsigned int h) {
    return __uint_as_float(h << 16);
}
__device__ __forceinline__ float bfhi(unsigned int h) {
    return __uint_as_float(h & 0xffff0000u);
}
__device__ __forceinline__ unsigned int f2bf(float f) {
    unsigned int u = __float_as_uint(f);
    return (u + 0x7fffu + ((u >> 16) & 1u)) >> 16;   // round-to-nearest-even
}
__device__ __forceinline__ unsigned int pack2(float a, float b) {
    return f2bf(a) | (f2bf(b) << 16);
}

// ---------------------------------------------------------------------------
// init: zero degree counters and BN stats accumulators (2 x [sum128|sumsq128])
__global__ __launch_bounds__(256) void k_init(int* __restrict__ deg_cnt,
                                              float* __restrict__ stats, int n) {
    int i = blockIdx.x * 256 + threadIdx.x;
    if (i < n) deg_cnt[i] = 0;
    if (i < 512) stats[i] = 0.0f;
}

// one-time: split W1,W2 (128x128 fp32) into bf16 hi/lo planes in MFMA
// B-fragment order: Wp[((k>>5)*4 + ((k>>3)&3))*128 + col][k&7].
__global__ __launch_bounds__(256) void k_wprep(const float* __restrict__ W1,
                                               unsigned short* __restrict__ W1h,
                                               unsigned short* __restrict__ W1l,
                                               const float* __restrict__ W2,
                                               unsigned short* __restrict__ W2h,
                                               unsigned short* __restrict__ W2l) {
    int idx = blockIdx.x * 256 + threadIdx.x;   // 16384
    int k = idx >> 7;
    int col = idx & 127;
    int dst = ((((k >> 5) * 4 + ((k >> 3) & 3)) * 128) + col) * 8 + (k & 7);
    {
        float v = W1[idx];
        unsigned int hi = f2bf(v);
        unsigned int lo = f2bf(v - __uint_as_float(hi << 16));
        W1h[dst] = (unsigned short)hi;
        W1l[dst] = (unsigned short)lo;
    }
    {
        float v = W2[idx];
        unsigned int hi = f2bf(v);
        unsigned int lo = f2bf(v - __uint_as_float(hi << 16));
        W2h[dst] = (unsigned short)hi;
        W2l[dst] = (unsigned short)lo;
    }
}

// in-degree histogram over dst; 4 edges/thread. NOW also records each edge's
// within-node ordinal (atomic return value) so the CSR fill needs NO atomic.
__global__ __launch_bounds__(256) void k_deg(const int* __restrict__ dst,
                                             int* __restrict__ deg_cnt,
                                             int* __restrict__ ord, int e) {
    int base = blockIdx.x * 1024 + threadIdx.x;
    int i0 = base, i1 = base + 256, i2 = base + 512, i3 = base + 768;
    int d0 = (i0 < e) ? dst[i0] : -1;
    int d1 = (i1 < e) ? dst[i1] : -1;
    int d2 = (i2 < e) ? dst[i2] : -1;
    int d3 = (i3 < e) ? dst[i3] : -1;
    int o0 = 0, o1 = 0, o2 = 0, o3 = 0;
    if (d0 >= 0) o0 = atomicAdd(&deg_cnt[d0], 1);
    if (d1 >= 0) o1 = atomicAdd(&deg_cnt[d1], 1);
    if (d2 >= 0) o2 = atomicAdd(&deg_cnt[d2], 1);
    if (d3 >= 0) o3 = atomicAdd(&deg_cnt[d3], 1);
    if (d0 >= 0) ord[i0] = o0;
    if (d1 >= 0) ord[i1] = o1;
    if (d2 >= 0) ord[i2] = o2;
    if (d3 >= 0) ord[i3] = o3;
}

// ---------------------------------------------------------------------------
__device__ __forceinline__ int wave_scan_incl(int v) {
    int lane = threadIdx.x & 63;
#pragma unroll
    for (int off = 1; off < 64; off <<= 1) {
        int t = __shfl_up(v, off, 64);
        if (lane >= off) v += t;
    }
    return v;
}

// stage 1: local exclusive scan -> row_start; block totals; also dinv
__global__ __launch_bounds__(256) void k_scan1(const int* __restrict__ deg_cnt,
                                               int* __restrict__ row_start,
                                               int* __restrict__ blk_sum,
                                               float* __restrict__ dinv, int n) {
    int tid = threadIdx.x;
    int i = blockIdx.x * 256 + tid;
    int v = (i < n) ? deg_cnt[i] : 0;
    if (i < n) dinv[i] = rsqrtf((float)v + 1.0f);   // fused: self-loop adds 1
    int inc = wave_scan_incl(v);
    __shared__ int wtot[4];
    int wave = tid >> 6, lane = tid & 63;
    if (lane == 63) wtot[wave] = inc;
    __syncthreads();
    int woff = 0;
    for (int w = 0; w < wave; ++w) woff += wtot[w];
    int excl = woff + inc - v;
    if (i < n) row_start[i] = excl;
    if (tid == 255) blk_sum[blockIdx.x] = woff + inc;
}

// stage 2+3 fused: each block redundantly reduces its exclusive block-prefix
// from blk_sum (nblk <= 256), applies it, block 0 writes the grand total.
__global__ __launch_bounds__(256) void k_scan3(int* __restrict__ row_start,
                                               const int* __restrict__ blk_sum,
                                               int n, int nblk) {
    __shared__ int wp[4], wv[4];
    __shared__ int s_off, s_tot;
    int tid = threadIdx.x;
    int v   = (tid < nblk) ? blk_sum[tid] : 0;
    int pre = (tid < (int)blockIdx.x) ? v : 0;
    int lane = tid & 63, wave = tid >> 6;
#pragma unroll
    for (int off = 32; off > 0; off >>= 1) {
        pre += __shfl_down(pre, off, 64);
        v   += __shfl_down(v,   off, 64);
    }
    if (lane == 0) { wp[wave] = pre; wv[wave] = v; }
    __syncthreads();
    if (tid == 0) {
        s_off = wp[0] + wp[1] + wp[2] + wp[3];
        s_tot = wv[0] + wv[1] + wv[2] + wv[3];
    }
    __syncthreads();
    int i = blockIdx.x * 256 + tid;
    if (i < n) row_start[i] += s_off;
    if (blockIdx.x == 0 && tid == 0) row_start[n] = s_tot;   // grand total
}

// ---------------------------------------------------------------------------
// MFMA GEMM tile (validated r8): H[r0b..r0b+63, :] = bf16( BNReLU?(X) @ W ).
// 3-MFMA hi/lo split for ~fp32 numerics. 4 waves of 32x64 each.
__device__ __forceinline__ void gemm_tile_mfma(
        const float* __restrict__ X,
        const unsigned short* __restrict__ Wh,
        const unsigned short* __restrict__ Wl,
        unsigned short* __restrict__ H,
        int n, int r0b,
        const float* __restrict__ bnsc,   // null -> raw X
        const float* __restrict__ bnsh,
        unsigned short (*xsh)[64][8],     // [4][64][8] 4 KB
        unsigned short (*xsl)[64][8]) {   // [4][64][8] 4 KB
    int t = threadIdx.x;
    int wid  = t >> 6;
    int lane = t & 63;
    int wrow = (wid & 1) * 32;
    int wcol = (wid >> 1) * 64;
    int lr = lane & 15;
    int kg = lane >> 4;
    bool bn = (bnsc != nullptr);

    const float4* X4 = (const float4*)X;
    f32x4 acc[2][4];
#pragma unroll
    for (int h = 0; h < 2; ++h)
#pragma unroll
        for (int c = 0; c < 4; ++c) acc[h][c] = (f32x4)0.f;

    for (int ks = 0; ks < 4; ++ks) {     // K-steps of 32
        if (ks) __syncthreads();
#pragma unroll
        for (int i = 0; i < 2; ++i) {
            int idx = t * 2 + i;         // 0..511
            int row = idx >> 3;          // 0..63
            int kq  = idx & 7;           // float4 within 32 k
            float4 v = make_float4(0.f, 0.f, 0.f, 0.f);
            if (r0b + row < n)
                v = X4[(size_t)(r0b + row) * 32 + ks * 8 + kq];
            if (bn) {
                int ch = ks * 32 + kq * 4;
                v.x = fmaxf(v.x * bnsc[ch + 0] + bnsh[ch + 0], 0.f);
                v.y = fmaxf(v.y * bnsc[ch + 1] + bnsh[ch + 1], 0.f);
                v.z = fmaxf(v.z * bnsc[ch + 2] + bnsh[ch + 2], 0.f);
                v.w = fmaxf(v.w * bnsc[ch + 3] + bnsh[ch + 3], 0.f);
            }
            unsigned int hx = f2bf(v.x), hy = f2bf(v.y), hz = f2bf(v.z), hw = f2bf(v.w);
            float rx = v.x - bflo(hx), ry = v.y - bflo(hy);
            float rz = v.z - bflo(hz), rw = v.w - bflo(hw);
            uint2 hp = make_uint2(hx | (hy << 16), hz | (hw << 16));
            uint2 lp = make_uint2(f2bf(rx) | (f2bf(ry) << 16), f2bf(rz) | (f2bf(rw) << 16));
            *(uint2*)&xsh[kq >> 1][row][(kq & 1) * 4] = hp;
            *(uint2*)&xsl[kq >> 1][row][(kq & 1) * 4] = lp;
        }
        __syncthreads();

        s16x8 Ah[2], Al[2];
#pragma unroll
        for (int h = 0; h < 2; ++h) {
            int row = wrow + h * 16 + lr;
            Ah[h] = *(const s16x8*)&xsh[kg][row][0];
            Al[h] = *(const s16x8*)&xsl[kg][row][0];
        }
#pragma unroll
        for (int c = 0; c < 4; ++c) {
            int col = wcol + c * 16 + lr;
            size_t boff = ((size_t)((ks * 4 + kg) * 128 + col)) * 8;
            s16x8 Bh = *(const s16x8*)&Wh[boff];
            s16x8 Bl = *(const s16x8*)&Wl[boff];
#pragma unroll
            for (int h = 0; h < 2; ++h) {
                acc[h][c] = __builtin_amdgcn_mfma_f32_16x16x32_bf16(Ah[h], Bh, acc[h][c], 0, 0, 0);
                acc[h][c] = __builtin_amdgcn_mfma_f32_16x16x32_bf16(Al[h], Bh, acc[h][c], 0, 0, 0);
                acc[h][c] = __builtin_amdgcn_mfma_f32_16x16x32_bf16(Ah[h], Bl, acc[h][c], 0, 0, 0);
            }
        }
    }
    // C/D layout: col = lane&15, row = (lane>>4)*4 + r  [HW-verified]
#pragma unroll
    for (int h = 0; h < 2; ++h)
#pragma unroll
        for (int c = 0; c < 4; ++c)
#pragma unroll
            for (int r = 0; r < 4; ++r) {
                int row = r0b + wrow + h * 16 + kg * 4 + r;
                if (row < n)
                    H[(size_t)row * DIM + wcol + c * 16 + lr] =
                        (unsigned short)f2bf(acc[h][c][r]);
            }
}

// ---------------------------------------------------------------------------
// FUSED fill || MFMA GEMM1. Fill is now ATOMIC-FREE: pos = row_start[dst] +
// precomputed ordinal -> fire-and-forget 8B scatter store; only L2-cached
// loads (row_start/dinv, 200 KB each) are on the latency path.
__global__ __launch_bounds__(256) void k_fill_gemm(
        const int* __restrict__ src, const int* __restrict__ dst,
        const int* __restrict__ ord,
        const float* __restrict__ dinv,
        const int* __restrict__ row_start,
        int2* __restrict__ edge, int e, int gemmBlocks,
        const float* __restrict__ X,
        const unsigned short* __restrict__ Wh,
        const unsigned short* __restrict__ Wl,
        unsigned short* __restrict__ H, int n) {
    __shared__ unsigned short xsh[4][64][8];   // 4 KB
    __shared__ unsigned short xsl[4][64][8];   // 4 KB

    int b = (int)blockIdx.x;
    bool isGemm = ((b & 1) == 0) && ((b >> 1) < gemmBlocks);
    if (!isGemm) {
        int nG = min(gemmBlocks, (b + 1) >> 1);   // gemm blocks before b
        int base = (b - nG) * 512 + threadIdx.x;
        int i0 = base, i1 = base + 256;
        bool v0 = i0 < e, v1 = i1 < e;
        int s0 = v0 ? src[i0] : 0, t0 = v0 ? dst[i0] : 0;
        int s1 = v1 ? src[i1] : 0, t1 = v1 ? dst[i1] : 0;
        int o0 = v0 ? ord[i0] : 0, o1 = v1 ? ord[i1] : 0;
        float w0 = v0 ? dinv[s0] * dinv[t0] : 0.f;
        float w1 = v1 ? dinv[s1] * dinv[t1] : 0.f;
        if (v0) edge[row_start[t0] + o0] = make_int2(s0, __float_as_int(w0));
        if (v1) edge[row_start[t1] + o1] = make_int2(s1, __float_as_int(w1));
        return;
    }
    gemm_tile_mfma(X, Wh, Wl, H, n, (b >> 1) * 64, nullptr, nullptr, xsh, xsl);
}

// ---------------------------------------------------------------------------
// MFMA GEMM for conv2 (BN1+ReLU fused into staging) — validated r8.
__global__ __launch_bounds__(256) void k_gemm_mfma(
        const float* __restrict__ X,
        const unsigned short* __restrict__ Wh,
        const unsigned short* __restrict__ Wl,
        const float* __restrict__ stats,
        const float* __restrict__ gamma,
        const float* __restrict__ beta,
        unsigned short* __restrict__ H,
        int n, float invN) {
    __shared__ unsigned short xsh[4][64][8];   // 4 KB
    __shared__ unsigned short xsl[4][64][8];   // 4 KB
    __shared__ float bnsc[DIM], bnsh[DIM];
    int t = threadIdx.x;
    if (t < DIM) {
        float mu = stats[t] * invN;
        float var = stats[DIM + t] * invN - mu * mu;
        float inv = rsqrtf(var + BN_EPS);
        float sc = gamma[t] * inv;
        bnsc[t] = sc;
        bnsh[t] = beta[t] - mu * sc;
    }
    __syncthreads();
    gemm_tile_mfma(X, Wh, Wl, H, n, blockIdx.x * 64, bnsc, bnsh, xsh, xsl);
}

// ---------------------------------------------------------------------------
// out[i,:] = sum_{j in in-edges(i)} H[edge[j].x,:]*edge[j].w + H[i,:]*dinv[i]^2 + bias
// ONE WAVE per node; 16-edge main unroll + 4-step mid + scalar tail.
// (round-0 measured-best form; 4 alternatives all measured worse)
__global__ __launch_bounds__(256) void k_agg(const unsigned int* __restrict__ Hp,
                                             const float* __restrict__ bias,
                                             const float* __restrict__ dinv,
                                             const int* __restrict__ row_start,
                                             const int2* __restrict__ edge,
                                             float* __restrict__ out, int n, int e) {
    int node = blockIdx.x * 4 + (threadIdx.x >> 6);
    int lane = threadIdx.x & 63;
    if (node >= n) return;
    float di = dinv[node];
    float dsq = di * di;
    float b0 = bias[2 * lane];
    float b1 = bias[2 * lane + 1];
    unsigned int hs = Hp[(size_t)node * 64 + lane];
    float a0 = bflo(hs) * dsq + b0;
    float a1 = bfhi(hs) * dsq + b1;
    int jb = row_start[node], je = row_start[node + 1];
    jb = min(max(jb, 0), e);
    je = min(max(je, jb), e);
    int j = jb;
    for (; j + 16 <= je; j += 16) {
        int2 ed[16]; unsigned int h[16];
#pragma unroll
        for (int u = 0; u < 16; ++u) ed[u] = edge[j + u];
#pragma unroll
        for (int u = 0; u < 16; ++u) h[u] = Hp[(size_t)ed[u].x * 64 + lane];
#pragma unroll
        for (int u = 0; u < 16; ++u) {
            float w = __int_as_float(ed[u].y);
            a0 += bflo(h[u]) * w;
            a1 += bfhi(h[u]) * w;
        }
    }
    for (; j + 4 <= je; j += 4) {
        int2 ed[4]; unsigned int h[4];
#pragma unroll
        for (int u = 0; u < 4; ++u) ed[u] = edge[j + u];
#pragma unroll
        for (int u = 0; u < 4; ++u) h[u] = Hp[(size_t)ed[u].x * 64 + lane];
#pragma unroll
        for (int u = 0; u < 4; ++u) {
            float w = __int_as_float(ed[u].y);
            a0 += bflo(h[u]) * w;
            a1 += bfhi(h[u]) * w;
        }
    }
    for (; j < je; ++j) {
        int2 ed = edge[j];
        float w = __int_as_float(ed.y);
        unsigned int h = Hp[(size_t)ed.x * 64 + lane];
        a0 += bflo(h) * w;
        a1 += bfhi(h) * w;
    }
    out[(size_t)node * DIM + 2 * lane]     = a0;
    out[(size_t)node * DIM + 2 * lane + 1] = a1;
}

// ---------------------------------------------------------------------------
// column sums + sums of squares; 64 rows/block for latency hiding
__global__ __launch_bounds__(256) void k_stats(const float* __restrict__ V,
                                               float* __restrict__ sums, int n) {
    int d = threadIdx.x & 127;
    int half = threadIdx.x >> 7;
    int r0 = blockIdx.x * 64;
    int r1 = min(r0 + 64, n);
    float s = 0.f, q = 0.f;
    for (int r = r0 + half; r < r1; r += 2) {
        float v = V[(size_t)r * DIM + d];
        s += v; q += v * v;
    }
    __shared__ float ls[256], lq[256];
    ls[threadIdx.x] = s; lq[threadIdx.x] = q;
    __syncthreads();
    if (half == 0) {
        atomicAdd(&sums[d], s + ls[threadIdx.x + 128]);
        atomicAdd(&sums[128 + d], q + lq[threadIdx.x + 128]);
    }
}

// ---------------------------------------------------------------------------
// BN + residual + ReLU -> out (grid-stride float4; safe when V == out).
__global__ __launch_bounds__(256) void k_bn_res_relu(const float* __restrict__ V,
                                                     const float* __restrict__ X,
                                                     const float* __restrict__ stats,
                                                     const float* __restrict__ gamma,
                                                     const float* __restrict__ beta,
                                                     float* __restrict__ out,
                                                     int n, float invN) {
    __shared__ float bnsc[DIM], bnsh[DIM];
    int t = threadIdx.x;
    if (t < DIM) {
        float mu = stats[t] * invN;
        float var = stats[DIM + t] * invN - mu * mu;
        float inv = rsqrtf(var + BN_EPS);
        float sc = gamma[t] * inv;
        bnsc[t] = sc;
        bnsh[t] = beta[t] - mu * sc;
    }
    __syncthreads();
    int total4 = n * (DIM / 4);
    const float4* V4 = (const float4*)V;
    const float4* X4 = (const float4*)X;
    float4* O4 = (float4*)out;
    for (int i = blockIdx.x * 256 + t; i < total4; i += gridDim.x * 256) {
        int c = (i & 31) * 4;
        float4 v = V4[i];
        float4 x = X4[i];
        float4 o;
        o.x = fmaxf(v.x * bnsc[c + 0] + bnsh[c + 0] + x.x, 0.f);
        o.y = fmaxf(v.y * bnsc[c + 1] + bnsh[c + 1] + x.y, 0.f);
        o.z = fmaxf(v.z * bnsc[c + 2] + bnsh[c + 2] + x.z, 0.f);
        o.w = fmaxf(v.w * bnsc[c + 3] + bnsh[c + 3] + x.w, 0.f);
        O4[i] = o;
    }
}

// ---------------------------------------------------------------------------
extern "C" void kernel_launch(void* const* d_in, const int* in_sizes, int n_in,
                              void* d_out, int out_size, void* d_ws, size_t ws_size,
                              hipStream_t stream) {
    const float* x      = (const float*)d_in[0];
    const int*   ei     = (const int*)d_in[1];
    const float* W1     = (const float*)d_in[2];
    const float* b1     = (const float*)d_in[3];
    const float* gamma1 = (const float*)d_in[4];
    const float* beta1  = (const float*)d_in[5];
    const float* W2     = (const float*)d_in[6];
    const float* b2     = (const float*)d_in[7];
    const float* gamma2 = (const float*)d_in[8];
    const float* beta2  = (const float*)d_in[9];
    float* out = (float*)d_out;

    int n = in_sizes[0] / DIM;   // 50000
    int e = in_sizes[1] / 2;     // 800000
    const int* srcIdx = ei;
    const int* dstIdx = ei + e;

    int gN      = (n + 255) / 256;
    int gE4     = (e + 1023) / 1024;
    int gF2     = (e + 511) / 512;
    int gRows64 = (n + 63) / 64;
    int gNode   = (n + 3) / 4;
    int gS      = (n + 63) / 64;
    int gFin    = 1536;
    float invN = 1.0f / (float)n;

    char* ws = (char*)d_ws;
    size_t off = 0;
    auto alloc = [&](size_t bytes) -> void* {
        void* p = ws + off;
        off += (bytes + 255) & ~(size_t)255;
        return p;
    };
    int*   deg_cnt   = (int*)  alloc((size_t)n * 4);
    float* dinv      = (float*)alloc((size_t)n * 4);
    int*   row_start = (int*)  alloc((size_t)(n + 1) * 4);
    int*   ord       = (int*)  alloc((size_t)e * 4);
    int*   blk_sum   = (int*)  alloc((size_t)gN * 4);
    int2*  edge      = (int2*) alloc((size_t)e * 8);
    unsigned short* Hb  = (unsigned short*)alloc((size_t)n * DIM * 2);
    unsigned short* W1h = (unsigned short*)alloc(16384 * 2);
    unsigned short* W1l = (unsigned short*)alloc(16384 * 2);
    unsigned short* W2h = (unsigned short*)alloc(16384 * 2);
    unsigned short* W2l = (unsigned short*)alloc(16384 * 2);
    float* stats     = (float*)alloc(512 * 4);
    float* stats1 = stats;
    float* stats2 = stats + 256;
    float* bufB = out;   // d_out doubles as fp32 N x D buffer

    if (off > ws_size || gN > 256) return;

    // graph preprocessing + one-time W1/W2 split/permute
    k_init<<<gN, 256, 0, stream>>>(deg_cnt, stats, n);
    k_wprep<<<64, 256, 0, stream>>>(W1, W1h, W1l, W2, W2h, W2l);
    k_deg<<<gE4, 256, 0, stream>>>(dstIdx, deg_cnt, ord, e);
    k_scan1<<<gN, 256, 0, stream>>>(deg_cnt, row_start, blk_sum, dinv, n);
    k_scan3<<<gN, 256, 0, stream>>>(row_start, blk_sum, n, gN);

    // FUSED: atomic-free CSR fill || MFMA GEMM1
    k_fill_gemm<<<gF2 + gRows64, 256, 0, stream>>>(
        srcIdx, dstIdx, ord, dinv, row_start, edge, e, gRows64,
        x, W1h, W1l, Hb, n);

    // conv1 aggregation + stats
    k_agg<<<gNode, 256, 0, stream>>>((const unsigned int*)Hb, b1, dinv, row_start, edge, bufB, n, e);
    k_stats<<<gS, 256, 0, stream>>>(bufB, stats1, n);

    // conv2: MFMA GEMM (BN1+ReLU fused into staging)
    k_gemm_mfma<<<gRows64, 256, 0, stream>>>(bufB, W2h, W2l, stats1, gamma1, beta1, Hb, n, invN);
    k_agg<<<gNode, 256, 0, stream>>>((const unsigned int*)Hb, b2, dinv, row_start, edge, bufB, n, e);
    k_stats<<<gS, 256, 0, stream>>>(bufB, stats2, n);
    k_bn_res_relu<<<gFin, 256, 0, stream>>>(bufB, x, stats2, gamma2, beta2, out, n, invN);
}